// Round 3
// baseline (439.037 us; speedup 1.0000x reference)
//
#include <hip/hip_runtime.h>

#define N_NODES 8192
#define M_NEI   32
#define K_PTS   8
#define D       64
#define EPS_    1e-7f

typedef float v2f __attribute__((ext_vector_type(2)));
typedef float v4f __attribute__((ext_vector_type(4)));

// D = S0*S1 + S2.  Broadcast src1.lo (or .hi) into both halves via op_sel.
#define PKFMA_LO(a, xx, ww) asm("v_pk_fma_f32 %0, %1, %2, %0 op_sel:[0,0,0] op_sel_hi:[1,0,1]" : "+v"(a) : "v"(xx), "v"(ww))
#define PKFMA_HI(a, xx, ww) asm("v_pk_fma_f32 %0, %1, %2, %0 op_sel:[0,1,0] op_sel_hi:[1,1,1]" : "+v"(a) : "v"(xx), "v"(ww))

// ---------------- prep: x_kernel rows (K x 64) ----------------
__global__ void prep_xk(const float* __restrict__ kp, float* __restrict__ xk) {
  int d = threadIdx.x;  // 64 threads
  for (int kk = 0; kk < K_PTS - 1; ++kk) {
    float v = kp[(kk + 1) * D + d];
    float p = (d == 0) ? 0.f : v * v;
    #pragma unroll
    for (int s = 1; s < 64; s <<= 1) p += __shfl_xor(p, s);
    float un = sqrtf(fmaxf(p, 1e-14f));
    float sh = sinhf(un) / un;
    xk[kk * D + d] = (d == 0) ? coshf(un) : sh * v;
  }
  xk[(K_PTS - 1) * D + d] = (d == 0) ? 1.f : 0.f;
}

// ---------------- prep: W transpose  Wt[d][k*64+o] = W[k][o][d] ----------------
__global__ void prep_wt(const float* __restrict__ W, float* __restrict__ Wt) {
  int idx = blockIdx.x * 256 + threadIdx.x;  // 32768 = 64*512
  int d = idx >> 9, ko = idx & 511;
  Wt[idx] = W[ko * D + d];
}

// ---------------- main: 512 threads = 8 waves, wave w owns m in [4w, 4w+4) ----------------
__launch_bounds__(512, 4)
__global__ void kpa_main(const float* __restrict__ x, const int* __restrict__ nei,
                         const int* __restrict__ mask, const float* __restrict__ Wt,
                         const float* __restrict__ b, const float* __restrict__ scale,
                         const float* __restrict__ xk, float* __restrict__ out) {
  __shared__ __align__(16) float xr_s[D];
  __shared__ __align__(16) float xk_s[K_PTS * D];     // 512
  __shared__ __align__(16) float x0t[D * M_NEI];      // [d][m] 8KB
  __shared__ float dis_s[K_PTS * 33];                 // pad -> conflict-free
  __shared__ __align__(16) float red[8 * D];          // per-wave partials

  const int n  = blockIdx.x;
  const int t  = threadIdx.x;   // 0..511
  const int w4 = t >> 6;        // wave 0..7
  const int l  = t & 63;

  if (t < D) xr_s[t] = x[n * D + t];
  xk_s[t] = xk[t];              // 512 threads, 512 elements
  __syncthreads();

  // ---- prologue: 16 lanes per neighbor; m = t>>4, l16 = t&15 owns d in [l16*4,+4)
  {
    const int m   = t >> 4;
    const int l16 = t & 15;
    const int d0  = l16 * 4;
    const int ni  = nei[n * M_NEI + m];
    v4f y4 = *(const v4f*)(x + ni * D + d0);
    v4f r4 = *(const v4f*)(xr_s + d0);
    float p = y4.x * r4.x + y4.y * r4.y + y4.z * r4.z + y4.w * r4.w;
    if (l16 == 0) p -= 2.f * y4.x * r4.x;
    p += __shfl_xor(p, 1); p += __shfl_xor(p, 2); p += __shfl_xor(p, 4); p += __shfl_xor(p, 8);
    float alpha = fmaxf(-p, 1.f + EPS_);
    float dd  = acoshf(alpha);
    float den = sqrtf(fmaxf(alpha * alpha - 1.f, 1e-14f));
    float f   = dd / den;
    v4f vv;
    vv.x = f * (y4.x - alpha * r4.x);
    vv.y = f * (y4.y - alpha * r4.y);
    vv.z = f * (y4.z - alpha * r4.z);
    vv.w = f * (y4.w - alpha * r4.w);
    float v0 = __shfl(vv.x, l & 48);          // l16==0 lane's d=0 value
    float c  = -v0 / (1.f + xr_s[0]);
    v4f wv;
    wv.x = vv.x + c * r4.x; wv.y = vv.y + c * r4.y;
    wv.z = vv.z + c * r4.z; wv.w = vv.w + c * r4.w;
    float q = wv.x * wv.x + wv.y * wv.y + wv.z * wv.z + wv.w * wv.w;
    if (l16 == 0) q -= wv.x * wv.x;           // spatial norm excludes d=0
    q += __shfl_xor(q, 1); q += __shfl_xor(q, 2); q += __shfl_xor(q, 4); q += __shfl_xor(q, 8);
    float un = sqrtf(fmaxf(q, 1e-14f));
    float sh = sinhf(un) / un;
    v4f x0;
    x0.x = sh * wv.x; x0.y = sh * wv.y; x0.z = sh * wv.z; x0.w = sh * wv.w;
    if (l16 == 0) x0.x = coshf(un);
    x0t[(d0 + 0) * M_NEI + m] = x0.x;
    x0t[(d0 + 1) * M_NEI + m] = x0.y;
    x0t[(d0 + 2) * M_NEI + m] = x0.z;
    x0t[(d0 + 3) * M_NEI + m] = x0.w;
    float msk = (float)mask[n * M_NEI + m];
    #pragma unroll
    for (int kk = 0; kk < K_PTS; ++kk) {
      const float* xkp = xk_s + kk * D + d0;
      float pp = x0.x * xkp[0] + x0.y * xkp[1] + x0.z * xkp[2] + x0.w * xkp[3];
      if (l16 == 0) pp -= 2.f * x0.x * xk_s[kk * D];
      pp += __shfl_xor(pp, 1); pp += __shfl_xor(pp, 2); pp += __shfl_xor(pp, 4); pp += __shfl_xor(pp, 8);
      float al = fmaxf(-pp, 1.f + EPS_);
      float dk = acoshf(al) * msk;
      if (l16 == kk) dis_s[kk * 33 + m] = dk;
    }
  }
  __syncthreads();

  // ---- matmul: lane -> k = l>>3, oct = l&7 (o = oct*8+j); wave -> m quartet.
  // acc2[mi2][j] packs m-pair {2*mi2, 2*mi2+1} for output column j.
  const int k   = l >> 3;
  const int oct = l & 7;
  v2f a2[2][8];
  #pragma unroll
  for (int i = 0; i < 2; ++i)
    #pragma unroll
    for (int j = 0; j < 8; ++j) { a2[i][j].x = 0.f; a2[i][j].y = 0.f; }

  const float* xbase = x0t + w4 * 4;
  const float* wbase = Wt + l * 8;
  #pragma unroll 4
  for (int d = 0; d < 64; ++d) {
    v4f xm = *(const v4f*)(xbase + d * 32);
    v4f wa = *(const v4f*)(wbase + d * 512);
    v4f wb = *(const v4f*)(wbase + d * 512 + 4);
    v2f x01 = __builtin_shufflevector(xm, xm, 0, 1);
    v2f x23 = __builtin_shufflevector(xm, xm, 2, 3);
    v2f w01 = __builtin_shufflevector(wa, wa, 0, 1);
    v2f w23 = __builtin_shufflevector(wa, wa, 2, 3);
    v2f w45 = __builtin_shufflevector(wb, wb, 0, 1);
    v2f w67 = __builtin_shufflevector(wb, wb, 2, 3);
    PKFMA_LO(a2[0][0], x01, w01); PKFMA_HI(a2[0][1], x01, w01);
    PKFMA_LO(a2[0][2], x01, w23); PKFMA_HI(a2[0][3], x01, w23);
    PKFMA_LO(a2[0][4], x01, w45); PKFMA_HI(a2[0][5], x01, w45);
    PKFMA_LO(a2[0][6], x01, w67); PKFMA_HI(a2[0][7], x01, w67);
    PKFMA_LO(a2[1][0], x23, w01); PKFMA_HI(a2[1][1], x23, w01);
    PKFMA_LO(a2[1][2], x23, w23); PKFMA_HI(a2[1][3], x23, w23);
    PKFMA_LO(a2[1][4], x23, w45); PKFMA_HI(a2[1][5], x23, w45);
    PKFMA_LO(a2[1][6], x23, w67); PKFMA_HI(a2[1][7], x23, w67);
  }
  // bias
  #pragma unroll
  for (int j = 0; j < 8; ++j) {
    float bvj = b[k * D + oct * 8 + j];
    a2[0][j].x += bvj; a2[0][j].y += bvj;
    a2[1][j].x += bvj; a2[1][j].y += bvj;
  }

  const float es = expf(scale[k]);
  float outacc[8];
  #pragma unroll
  for (int j = 0; j < 8; ++j) outacc[j] = 0.f;

  #pragma unroll
  for (int mi = 0; mi < 4; ++mi) {
    float aj[8];
    #pragma unroll
    for (int j = 0; j < 8; ++j) aj[j] = (mi & 1) ? a2[mi >> 1][j].y : a2[mi >> 1][j].x;
    const int m = w4 * 4 + mi;
    float dm = dis_s[k * 33 + m];
    float h0 = __shfl(aj[0], l & 56);   // oct==0 lane of this k-group
    float nar2 = 0.f;
    #pragma unroll
    for (int j = 0; j < 8; ++j) nar2 += aj[j] * aj[j];
    if (oct == 0) nar2 -= aj[0] * aj[0];
    nar2 += __shfl_xor(nar2, 1); nar2 += __shfl_xor(nar2, 2); nar2 += __shfl_xor(nar2, 4);
    float time = es / (1.f + expf(-h0)) + 1.0001f;
    float s  = (time * time - 1.f) / fmaxf(nar2, 1e-8f);
    float sq = sqrtf(s);
    float yv[8];
    #pragma unroll
    for (int j = 0; j < 8; ++j) yv[j] = dm * (aj[j] * sq);
    if (oct == 0) yv[0] = dm * time;
    // sum over k (lane bits 3..5)
    #pragma unroll
    for (int j = 0; j < 8; ++j) {
      float z = yv[j];
      z += __shfl_xor(z, 8); z += __shfl_xor(z, 16); z += __shfl_xor(z, 32);
      yv[j] = z;
    }
    // l_inner(ave,ave) over o (reduce over oct groups)
    float ip = 0.f;
    #pragma unroll
    for (int j = 0; j < 8; ++j) ip += yv[j] * yv[j];
    if (oct == 0) ip -= 2.f * yv[0] * yv[0];
    ip += __shfl_xor(ip, 1); ip += __shfl_xor(ip, 2); ip += __shfl_xor(ip, 4);
    float rin = 1.f / sqrtf(fmaxf(fabsf(ip), 1e-8f));
    #pragma unroll
    for (int j = 0; j < 8; ++j) outacc[j] += yv[j] * rin;
  }
  if (l < 8) {
    #pragma unroll
    for (int j = 0; j < 8; ++j) red[w4 * D + l * 8 + j] = outacc[j];
  }
  __syncthreads();
  if (t < D) {
    float sm = 0.f;
    #pragma unroll
    for (int w = 0; w < 8; ++w) sm += red[w * D + t];
    float mv = sm * (1.f / 32.f);
    float ip = (t == 0) ? -mv * mv : mv * mv;
    #pragma unroll
    for (int s2 = 1; s2 < 64; s2 <<= 1) ip += __shfl_xor(ip, s2);
    out[n * D + t] = mv / sqrtf(fmaxf(fabsf(ip), 1e-8f));
  }
}

extern "C" void kernel_launch(void* const* d_in, const int* in_sizes, int n_in,
                              void* d_out, int out_size, void* d_ws, size_t ws_size,
                              hipStream_t stream) {
  const float* x     = (const float*)d_in[0];
  const int*   nei   = (const int*)d_in[1];
  const int*   mask  = (const int*)d_in[2];
  const float* W     = (const float*)d_in[3];
  const float* b     = (const float*)d_in[4];
  const float* scale = (const float*)d_in[5];
  const float* kp    = (const float*)d_in[6];
  float* out = (float*)d_out;

  float* Wt = (float*)d_ws;            // 64*512 floats = 128 KiB
  float* xk = Wt + 64 * 512;           // 8*64 floats

  prep_wt<<<128, 256, 0, stream>>>(W, Wt);
  prep_xk<<<1, 64, 0, stream>>>(kp, xk);
  kpa_main<<<N_NODES, 512, 0, stream>>>(x, nei, mask, Wt, b, scale, xk, out);
}

// Round 4
// 200.522 us; speedup vs baseline: 2.1895x; 2.1895x over previous
//
#include <hip/hip_runtime.h>
#include <hip/hip_bf16.h>

#define N_NODES 8192
#define M_NEI   32
#define K_PTS   8
#define D       64
#define EPS_    1e-7f

typedef float f4v __attribute__((ext_vector_type(4)));
typedef short s8v __attribute__((ext_vector_type(8)));

__device__ __forceinline__ ushort f2bf(float f) {
  __hip_bfloat16 h = __float2bfloat16(f);
  return *reinterpret_cast<ushort*>(&h);
}
__device__ __forceinline__ float bf2f(ushort u) {
  __hip_bfloat16 h;
  *reinterpret_cast<ushort*>(&h) = u;
  return __bfloat162float(h);
}

// ---------------- prep: x_kernel rows (K x 64) ----------------
__global__ void prep_xk(const float* __restrict__ kp, float* __restrict__ xk) {
  int d = threadIdx.x;  // 64 threads
  for (int kk = 0; kk < K_PTS - 1; ++kk) {
    float v = kp[(kk + 1) * D + d];
    float p = (d == 0) ? 0.f : v * v;
    #pragma unroll
    for (int s = 1; s < 64; s <<= 1) p += __shfl_xor(p, s);
    float un = sqrtf(fmaxf(p, 1e-14f));
    float sh = sinhf(un) / un;
    xk[kk * D + d] = (d == 0) ? coshf(un) : sh * v;
  }
  xk[(K_PTS - 1) * D + d] = (d == 0) ? 1.f : 0.f;
}

// ---------------- prep: W -> bf16 hi/lo MFMA B-fragments ----------------
// Frag f = (k*4+ct)*2+ks.  B[d][o] = W[k][o][d].  Lane holds col=lane&15
// (o = ct*16+col), k-dim d = (lane>>4)*8 + j + ks*32, j=0..7 ascending.
__global__ void prep_wb(const float* __restrict__ W, ushort* __restrict__ WF) {
  int idx = blockIdx.x * 256 + threadIdx.x;   // 4096 total
  int k    = idx >> 9;
  int ct   = (idx >> 7) & 3;
  int ks   = (idx >> 6) & 1;
  int lane = idx & 63;
  int o  = ct * 16 + (lane & 15);
  int db = (lane >> 4) * 8 + ks * 32;
  const float* wrow = W + (k * 64 + o) * 64 + db;   // d-contiguous
  s8v hi, lo;
  #pragma unroll
  for (int j = 0; j < 8; ++j) {
    float w = wrow[j];
    ushort h = f2bf(w);
    hi[j] = (short)h;
    lo[j] = (short)f2bf(w - bf2f(h));
  }
  int f = (k * 4 + ct) * 2 + ks;
  *(s8v*)(WF + (size_t)(f * 2 + 0) * 512 + lane * 8) = hi;
  *(s8v*)(WF + (size_t)(f * 2 + 1) * 512 + lane * 8) = lo;
}

// ---------------- main: 256 threads = 4 waves; wave w handles k = w, w+4 ----------------
__launch_bounds__(256, 3)
__global__ void kpa_main(const float* __restrict__ x, const int* __restrict__ nei,
                         const int* __restrict__ mask, const ushort* __restrict__ WF,
                         const float* __restrict__ b, const float* __restrict__ scale,
                         const float* __restrict__ xk, float* __restrict__ out) {
  __shared__ __align__(16) float  xr_s[D];
  __shared__ __align__(16) float  xk_s[K_PTS * D];
  __shared__ __align__(16) ushort Ah_lds[M_NEI * D];     // bf16 hi, XOR-swizzled
  __shared__ __align__(16) ushort Al_lds[M_NEI * D];     // bf16 lo
  __shared__ float dis_s[K_PTS * 33];
  __shared__ __align__(16) float  red_w[4][M_NEI * 66];  // per-wave per_nei partials (padded)
  __shared__ __align__(16) float  redp[4 * D];           // per-wave mean partials

  const int n  = blockIdx.x;
  const int t  = threadIdx.x;
  const int w4 = t >> 6;     // wave 0..3
  const int l  = t & 63;
  const int cl = l & 15;     // MFMA col / row-in-tile index
  const int gr = l >> 4;     // MFMA k-group / row-subgroup

  if (t < D) xr_s[t] = x[n * D + t];
  xk_s[t] = xk[t]; xk_s[t + 256] = xk[t + 256];
  __syncthreads();

  // ---- prologue: 8 lanes per neighbor; m = t>>3, l8 = t&7 owns d in [l8*8,+8)
  {
    const int m  = t >> 3;
    const int l8 = t & 7;
    const int d0 = l8 * 8;
    const int ni = nei[n * M_NEI + m];
    float y[8], xr[8];
    {
      float4 ya = *(const float4*)(x + ni * D + d0);
      float4 yb = *(const float4*)(x + ni * D + d0 + 4);
      y[0]=ya.x; y[1]=ya.y; y[2]=ya.z; y[3]=ya.w;
      y[4]=yb.x; y[5]=yb.y; y[6]=yb.z; y[7]=yb.w;
      float4 ra = *(const float4*)(xr_s + d0);
      float4 rb = *(const float4*)(xr_s + d0 + 4);
      xr[0]=ra.x; xr[1]=ra.y; xr[2]=ra.z; xr[3]=ra.w;
      xr[4]=rb.x; xr[5]=rb.y; xr[6]=rb.z; xr[7]=rb.w;
    }
    float p = 0.f;
    #pragma unroll
    for (int j = 0; j < 8; ++j) p += xr[j] * y[j];
    if (l8 == 0) p -= 2.f * xr[0] * y[0];
    p += __shfl_xor(p, 1); p += __shfl_xor(p, 2); p += __shfl_xor(p, 4);
    float alpha = fmaxf(-p, 1.f + EPS_);
    float dd  = acoshf(alpha);
    float den = sqrtf(fmaxf(alpha * alpha - 1.f, 1e-14f));
    float f   = dd / den;
    float v[8];
    #pragma unroll
    for (int j = 0; j < 8; ++j) v[j] = f * (y[j] - alpha * xr[j]);
    float v0 = __shfl(v[0], l & 56);
    float c  = -v0 / (1.f + xr_s[0]);
    float wv[8];
    float q = 0.f;
    #pragma unroll
    for (int j = 0; j < 8; ++j) { wv[j] = v[j] + c * xr[j]; q += wv[j] * wv[j]; }
    if (l8 == 0) q -= wv[0] * wv[0];
    q += __shfl_xor(q, 1); q += __shfl_xor(q, 2); q += __shfl_xor(q, 4);
    float un = sqrtf(fmaxf(q, 1e-14f));
    float sh = sinhf(un) / un;
    float x0v[8];
    #pragma unroll
    for (int j = 0; j < 8; ++j) x0v[j] = sh * wv[j];
    if (l8 == 0) x0v[0] = coshf(un);
    // A-tile: bf16 hi/lo, row m, bytes [m*128 + d0*2, +16), swizzle ^((m&7)<<4)
    {
      s8v hi, lo;
      #pragma unroll
      for (int j = 0; j < 8; ++j) {
        ushort h = f2bf(x0v[j]);
        hi[j] = (short)h;
        lo[j] = (short)f2bf(x0v[j] - bf2f(h));
      }
      int byte = m * 128 + d0 * 2;
      int swz  = byte ^ ((m & 7) << 4);
      *(s8v*)((char*)Ah_lds + swz) = hi;
      *(s8v*)((char*)Al_lds + swz) = lo;
    }
    float msk = (float)mask[n * M_NEI + m];
    #pragma unroll
    for (int kk = 0; kk < K_PTS; ++kk) {
      float pp = 0.f;
      #pragma unroll
      for (int j = 0; j < 8; ++j) pp += x0v[j] * xk_s[kk * D + d0 + j];
      if (l8 == 0) pp -= 2.f * x0v[0] * xk_s[kk * D];
      pp += __shfl_xor(pp, 1); pp += __shfl_xor(pp, 2); pp += __shfl_xor(pp, 4);
      float al = fmaxf(-pp, 1.f + EPS_);
      float dk = acoshf(al) * msk;
      if (l8 == kk) dis_s[kk * 33 + m] = dk;
    }
  }
  __syncthreads();

  // ---- MFMA passes: wave w4 does k = w4, then k = w4+4
  for (int p = 0; p < 2; ++p) {
    const int k = w4 + p * 4;
    s8v bh[4][2], bl[4][2];
    #pragma unroll
    for (int ct = 0; ct < 4; ++ct)
      #pragma unroll
      for (int ks = 0; ks < 2; ++ks) {
        int f = (k * 4 + ct) * 2 + ks;
        bh[ct][ks] = *(const s8v*)(WF + (size_t)(f * 2 + 0) * 512 + l * 8);
        bl[ct][ks] = *(const s8v*)(WF + (size_t)(f * 2 + 1) * 512 + l * 8);
      }
    f4v acc[4][2];
    #pragma unroll
    for (int ct = 0; ct < 4; ++ct)
      #pragma unroll
      for (int rt = 0; rt < 2; ++rt)
        acc[ct][rt] = (f4v){0.f, 0.f, 0.f, 0.f};

    #pragma unroll
    for (int rt = 0; rt < 2; ++rt) {
      const int row = cl + rt * 16;
      s8v ah[2], al_[2];
      #pragma unroll
      for (int ks = 0; ks < 2; ++ks) {
        int byte = row * 128 + (gr * 8 + ks * 32) * 2;
        int swz  = byte ^ ((row & 7) << 4);
        ah[ks]  = *(const s8v*)((const char*)Ah_lds + swz);
        al_[ks] = *(const s8v*)((const char*)Al_lds + swz);
      }
      #pragma unroll
      for (int ct = 0; ct < 4; ++ct)
        #pragma unroll
        for (int ks = 0; ks < 2; ++ks) {
          acc[ct][rt] = __builtin_amdgcn_mfma_f32_16x16x32_bf16(ah[ks],  bh[ct][ks], acc[ct][rt], 0, 0, 0);
          acc[ct][rt] = __builtin_amdgcn_mfma_f32_16x16x32_bf16(ah[ks],  bl[ct][ks], acc[ct][rt], 0, 0, 0);
          acc[ct][rt] = __builtin_amdgcn_mfma_f32_16x16x32_bf16(al_[ks], bh[ct][ks], acc[ct][rt], 0, 0, 0);
          acc[ct][rt] = __builtin_amdgcn_mfma_f32_16x16x32_bf16(al_[ks], bl[ct][ks], acc[ct][rt], 0, 0, 0);
        }
    }

    // bias
    float bv[4];
    #pragma unroll
    for (int ct = 0; ct < 4; ++ct) bv[ct] = b[k * 64 + ct * 16 + cl];
    #pragma unroll
    for (int ct = 0; ct < 4; ++ct)
      #pragma unroll
      for (int rt = 0; rt < 2; ++rt)
        #pragma unroll
        for (int r = 0; r < 4; ++r) acc[ct][rt][r] += bv[ct];

    const float es = expf(scale[k]);
    // epilogue: C layout col=cl, row = rt*16 + gr*4 + r  (HW-verified m89)
    #pragma unroll
    for (int rt = 0; rt < 2; ++rt)
      #pragma unroll
      for (int r = 0; r < 4; ++r) {
        const int m = rt * 16 + gr * 4 + r;
        float h0 = __shfl(acc[0][rt][r], l & 48);
        float ss = acc[0][rt][r]*acc[0][rt][r] + acc[1][rt][r]*acc[1][rt][r]
                 + acc[2][rt][r]*acc[2][rt][r] + acc[3][rt][r]*acc[3][rt][r];
        ss += __shfl_xor(ss, 1); ss += __shfl_xor(ss, 2);
        ss += __shfl_xor(ss, 4); ss += __shfl_xor(ss, 8);
        float nar2 = fmaxf(ss - h0 * h0, 1e-8f);
        float time = es / (1.f + expf(-h0)) + 1.0001f;
        float sq   = sqrtf((time * time - 1.f) / nar2);
        float dm   = dis_s[k * 33 + m];
        float c0 = (cl == 0) ? dm * time : dm * sq * acc[0][rt][r];
        float* rw = &red_w[w4][m * 66];
        if (p == 0) {
          rw[cl]      = c0;
          rw[16 + cl] = dm * sq * acc[1][rt][r];
          rw[32 + cl] = dm * sq * acc[2][rt][r];
          rw[48 + cl] = dm * sq * acc[3][rt][r];
        } else {
          rw[cl]      += c0;
          rw[16 + cl] += dm * sq * acc[1][rt][r];
          rw[32 + cl] += dm * sq * acc[2][rt][r];
          rw[48 + cl] += dm * sq * acc[3][rt][r];
        }
      }
  }
  __syncthreads();

  // ---- final: normalize per (m), mean over m, normalize per node (deterministic)
  {
    const int m  = t >> 3;
    const int l8 = t & 7;
    const int o0 = l8 * 8;
    float v[8];
    #pragma unroll
    for (int j = 0; j < 8; ++j) {
      v[j] = red_w[0][m * 66 + o0 + j] + red_w[1][m * 66 + o0 + j]
           + red_w[2][m * 66 + o0 + j] + red_w[3][m * 66 + o0 + j];
    }
    float ip = 0.f;
    #pragma unroll
    for (int j = 0; j < 8; ++j) ip += v[j] * v[j];
    if (l8 == 0) ip -= 2.f * v[0] * v[0];
    ip += __shfl_xor(ip, 1); ip += __shfl_xor(ip, 2); ip += __shfl_xor(ip, 4);
    float rin = 1.f / sqrtf(fmaxf(fabsf(ip), 1e-8f));
    #pragma unroll
    for (int j = 0; j < 8; ++j) {
      float z = v[j] * rin;
      z += __shfl_xor(z, 8); z += __shfl_xor(z, 16); z += __shfl_xor(z, 32);
      v[j] = z;   // sum over this wave's 8 m
    }
    if (l < 8) {
      #pragma unroll
      for (int j = 0; j < 8; ++j) redp[w4 * D + l8 * 8 + j] = v[j];
    }
  }
  __syncthreads();
  if (t < D) {
    float mv = (redp[t] + redp[D + t] + redp[2 * D + t] + redp[3 * D + t]) * (1.f / 32.f);
    float ip = (t == 0) ? -mv * mv : mv * mv;
    #pragma unroll
    for (int s2 = 1; s2 < 64; s2 <<= 1) ip += __shfl_xor(ip, s2);
    out[n * D + t] = mv / sqrtf(fmaxf(fabsf(ip), 1e-8f));
  }
}

extern "C" void kernel_launch(void* const* d_in, const int* in_sizes, int n_in,
                              void* d_out, int out_size, void* d_ws, size_t ws_size,
                              hipStream_t stream) {
  const float* x     = (const float*)d_in[0];
  const int*   nei   = (const int*)d_in[1];
  const int*   mask  = (const int*)d_in[2];
  const float* W     = (const float*)d_in[3];
  const float* b     = (const float*)d_in[4];
  const float* scale = (const float*)d_in[5];
  const float* kp    = (const float*)d_in[6];
  float* out = (float*)d_out;

  ushort* WF = (ushort*)d_ws;               // 64 frags x 2 parts x 512 ushort = 128 KiB
  float*  xk = (float*)(WF + 65536);        // 8*64 floats

  prep_wb<<<16, 256, 0, stream>>>(W, WF);
  prep_xk<<<1, 64, 0, stream>>>(kp, xk);
  kpa_main<<<N_NODES, 256, 0, stream>>>(x, nei, mask, WF, b, scale, xk, out);
}

// Round 5
// 124.523 us; speedup vs baseline: 3.5257x; 1.6103x over previous
//
#include <hip/hip_runtime.h>
#include <hip/hip_bf16.h>

#define N_NODES 8192
#define M_NEI   32
#define K_PTS   8
#define D       64
#define EPS_    1e-7f

typedef float f4v __attribute__((ext_vector_type(4)));
typedef short s8v __attribute__((ext_vector_type(8)));

__device__ __forceinline__ ushort f2bf(float f) {
  __hip_bfloat16 h = __float2bfloat16(f);
  return *reinterpret_cast<ushort*>(&h);
}
__device__ __forceinline__ float bf2f(ushort u) {
  __hip_bfloat16 h;
  *reinterpret_cast<ushort*>(&h) = u;
  return __bfloat162float(h);
}
// fast math: raw HW ops (1-ulp class)
__device__ __forceinline__ float frcp(float x)  { return __builtin_amdgcn_rcpf(x); }
__device__ __forceinline__ float frsq(float x)  { return __builtin_amdgcn_rsqf(x); }
__device__ __forceinline__ float fsqrt(float x) { return __builtin_amdgcn_sqrtf(x); }
// acosh(a) = log(a + sqrt(a^2-1)), a >= 1+eps
__device__ __forceinline__ float facosh(float a) {
  float den = fsqrt(fmaxf(a * a - 1.f, 1e-14f));
  return __logf(a + den);
}

// ---------------- prep: x_kernel rows (K x 64) ----------------
__global__ void prep_xk(const float* __restrict__ kp, float* __restrict__ xk) {
  int d = threadIdx.x;  // 64 threads
  for (int kk = 0; kk < K_PTS - 1; ++kk) {
    float v = kp[(kk + 1) * D + d];
    float p = (d == 0) ? 0.f : v * v;
    #pragma unroll
    for (int s = 1; s < 64; s <<= 1) p += __shfl_xor(p, s);
    float un = sqrtf(fmaxf(p, 1e-14f));
    float sh = sinhf(un) / un;
    xk[kk * D + d] = (d == 0) ? coshf(un) : sh * v;
  }
  xk[(K_PTS - 1) * D + d] = (d == 0) ? 1.f : 0.f;
}

// ---------------- prep: W -> bf16 hi/lo MFMA B-fragments ----------------
__global__ void prep_wb(const float* __restrict__ W, ushort* __restrict__ WF) {
  int idx = blockIdx.x * 256 + threadIdx.x;   // 4096 total
  int k    = idx >> 9;
  int ct   = (idx >> 7) & 3;
  int ks   = (idx >> 6) & 1;
  int lane = idx & 63;
  int o  = ct * 16 + (lane & 15);
  int db = (lane >> 4) * 8 + ks * 32;
  const float* wrow = W + (k * 64 + o) * 64 + db;   // d-contiguous
  s8v hi, lo;
  #pragma unroll
  for (int j = 0; j < 8; ++j) {
    float w = wrow[j];
    ushort h = f2bf(w);
    hi[j] = (short)h;
    lo[j] = (short)f2bf(w - bf2f(h));
  }
  int f = (k * 4 + ct) * 2 + ks;
  *(s8v*)(WF + (size_t)(f * 2 + 0) * 512 + lane * 8) = hi;
  *(s8v*)(WF + (size_t)(f * 2 + 1) * 512 + lane * 8) = lo;
}

// ---------------- main: 256 threads = 4 waves; wave w handles k = w, w+4 ----------------
__launch_bounds__(256, 3)
__global__ void kpa_main(const float* __restrict__ x, const int* __restrict__ nei,
                         const int* __restrict__ mask, const ushort* __restrict__ WF,
                         const float* __restrict__ b, const float* __restrict__ scale,
                         const float* __restrict__ xk, float* __restrict__ out) {
  __shared__ __align__(16) float  xr_s[D];
  __shared__ __align__(16) float  xk_s[K_PTS * D];
  __shared__ __align__(16) ushort Ah_lds[M_NEI * D];     // bf16 hi, XOR-swizzled
  __shared__ __align__(16) ushort Al_lds[M_NEI * D];     // bf16 lo
  __shared__ float dis_s[K_PTS * 33];
  __shared__ __align__(16) float  red_w[4][M_NEI * 68];  // per-wave per_nei partials
  __shared__ __align__(16) float  redp[4 * D];           // per-wave mean partials

  const int n  = blockIdx.x;
  const int t  = threadIdx.x;
  const int w4 = t >> 6;     // wave 0..3
  const int l  = t & 63;
  const int cl = l & 15;     // MFMA col index
  const int gr = l >> 4;     // MFMA k-group / row-subgroup

  if (t < D) xr_s[t] = x[n * D + t];
  xk_s[t] = xk[t]; xk_s[t + 256] = xk[t + 256];
  __syncthreads();

  // ---- prologue: 8 lanes per neighbor; m = t>>3, l8 = t&7 owns d in [l8*8,+8)
  {
    const int m  = t >> 3;
    const int l8 = t & 7;
    const int d0 = l8 * 8;
    const int ni = nei[n * M_NEI + m];
    float y[8], xr[8];
    {
      float4 ya = *(const float4*)(x + ni * D + d0);
      float4 yb = *(const float4*)(x + ni * D + d0 + 4);
      y[0]=ya.x; y[1]=ya.y; y[2]=ya.z; y[3]=ya.w;
      y[4]=yb.x; y[5]=yb.y; y[6]=yb.z; y[7]=yb.w;
      float4 ra = *(const float4*)(xr_s + d0);
      float4 rb = *(const float4*)(xr_s + d0 + 4);
      xr[0]=ra.x; xr[1]=ra.y; xr[2]=ra.z; xr[3]=ra.w;
      xr[4]=rb.x; xr[5]=rb.y; xr[6]=rb.z; xr[7]=rb.w;
    }
    float p = 0.f;
    #pragma unroll
    for (int j = 0; j < 8; ++j) p += xr[j] * y[j];
    if (l8 == 0) p -= 2.f * xr[0] * y[0];
    p += __shfl_xor(p, 1); p += __shfl_xor(p, 2); p += __shfl_xor(p, 4);
    float alpha = fmaxf(-p, 1.f + EPS_);
    float den = fsqrt(fmaxf(alpha * alpha - 1.f, 1e-14f));
    float dd  = __logf(alpha + den);          // acosh(alpha)
    float f   = dd * frcp(den);
    float v[8];
    #pragma unroll
    for (int j = 0; j < 8; ++j) v[j] = f * (y[j] - alpha * xr[j]);
    float v0 = __shfl(v[0], l & 56);
    float c  = -v0 * frcp(1.f + xr_s[0]);
    float wv[8];
    float q = 0.f;
    #pragma unroll
    for (int j = 0; j < 8; ++j) { wv[j] = v[j] + c * xr[j]; q += wv[j] * wv[j]; }
    if (l8 == 0) q -= wv[0] * wv[0];
    q += __shfl_xor(q, 1); q += __shfl_xor(q, 2); q += __shfl_xor(q, 4);
    float un = fsqrt(fmaxf(q, 1e-14f));
    float e  = __expf(un);
    float ei = frcp(e);
    float sh = (0.5f * (e - ei)) * frcp(un);  // sinh(un)/un
    float x0v[8];
    #pragma unroll
    for (int j = 0; j < 8; ++j) x0v[j] = sh * wv[j];
    if (l8 == 0) x0v[0] = 0.5f * (e + ei);    // cosh(un)
    // A-tile: bf16 hi/lo via truncation split, XOR-swizzled
    {
      s8v hi, lo;
      #pragma unroll
      for (int j = 0; j < 8; ++j) {
        uint u = __float_as_uint(x0v[j]);
        hi[j] = (short)(ushort)(u >> 16);
        float lof = x0v[j] - __uint_as_float(u & 0xffff0000u);
        uint ul = __float_as_uint(lof);
        lo[j] = (short)(ushort)((ul + 0x7fffu + ((ul >> 16) & 1u)) >> 16);
      }
      int byte = m * 128 + d0 * 2;
      int swz  = byte ^ ((m & 7) << 4);
      *(s8v*)((char*)Ah_lds + swz) = hi;
      *(s8v*)((char*)Al_lds + swz) = lo;
    }
    float msk = (float)mask[n * M_NEI + m];
    #pragma unroll
    for (int kk = 0; kk < K_PTS; ++kk) {
      float pp = 0.f;
      #pragma unroll
      for (int j = 0; j < 8; ++j) pp += x0v[j] * xk_s[kk * D + d0 + j];
      if (l8 == 0) pp -= 2.f * x0v[0] * xk_s[kk * D];
      pp += __shfl_xor(pp, 1); pp += __shfl_xor(pp, 2); pp += __shfl_xor(pp, 4);
      float al = fmaxf(-pp, 1.f + EPS_);
      float dk = facosh(al) * msk;
      if (l8 == kk) dis_s[kk * 33 + m] = dk;
    }
  }
  __syncthreads();

  // ---- MFMA passes: wave w4 does k = w4, then k = w4+4; accumulate output in regs
  float yacc[2][4][4];   // [rt][r][ct]
  #pragma unroll
  for (int rt = 0; rt < 2; ++rt)
    #pragma unroll
    for (int r = 0; r < 4; ++r)
      #pragma unroll
      for (int ct = 0; ct < 4; ++ct) yacc[rt][r][ct] = 0.f;

  #pragma unroll
  for (int p = 0; p < 2; ++p) {
    const int k = w4 + p * 4;
    s8v bh[4][2], bl[4][2];
    #pragma unroll
    for (int ct = 0; ct < 4; ++ct)
      #pragma unroll
      for (int ks = 0; ks < 2; ++ks) {
        int f = (k * 4 + ct) * 2 + ks;
        bh[ct][ks] = *(const s8v*)(WF + (size_t)(f * 2 + 0) * 512 + l * 8);
        bl[ct][ks] = *(const s8v*)(WF + (size_t)(f * 2 + 1) * 512 + l * 8);
      }
    f4v acc[4][2];
    #pragma unroll
    for (int ct = 0; ct < 4; ++ct)
      #pragma unroll
      for (int rt = 0; rt < 2; ++rt)
        acc[ct][rt] = (f4v){0.f, 0.f, 0.f, 0.f};

    #pragma unroll
    for (int rt = 0; rt < 2; ++rt) {
      const int row = cl + rt * 16;
      s8v ah[2], al_[2];
      #pragma unroll
      for (int ks = 0; ks < 2; ++ks) {
        int byte = row * 128 + (gr * 8 + ks * 32) * 2;
        int swz  = byte ^ ((row & 7) << 4);
        ah[ks]  = *(const s8v*)((const char*)Ah_lds + swz);
        al_[ks] = *(const s8v*)((const char*)Al_lds + swz);
      }
      #pragma unroll
      for (int ct = 0; ct < 4; ++ct)
        #pragma unroll
        for (int ks = 0; ks < 2; ++ks) {
          acc[ct][rt] = __builtin_amdgcn_mfma_f32_16x16x32_bf16(ah[ks],  bh[ct][ks], acc[ct][rt], 0, 0, 0);
          acc[ct][rt] = __builtin_amdgcn_mfma_f32_16x16x32_bf16(ah[ks],  bl[ct][ks], acc[ct][rt], 0, 0, 0);
          acc[ct][rt] = __builtin_amdgcn_mfma_f32_16x16x32_bf16(al_[ks], bh[ct][ks], acc[ct][rt], 0, 0, 0);
        }
    }

    // bias
    float bv[4];
    #pragma unroll
    for (int ct = 0; ct < 4; ++ct) bv[ct] = b[k * 64 + ct * 16 + cl];
    #pragma unroll
    for (int ct = 0; ct < 4; ++ct)
      #pragma unroll
      for (int rt = 0; rt < 2; ++rt)
        #pragma unroll
        for (int r = 0; r < 4; ++r) acc[ct][rt][r] += bv[ct];

    const float es = __expf(scale[k]);
    // epilogue: C layout col=cl, row = rt*16 + gr*4 + r
    #pragma unroll
    for (int rt = 0; rt < 2; ++rt)
      #pragma unroll
      for (int r = 0; r < 4; ++r) {
        const int m = rt * 16 + gr * 4 + r;
        float h0 = __shfl(acc[0][rt][r], l & 48);
        float ss = acc[0][rt][r]*acc[0][rt][r] + acc[1][rt][r]*acc[1][rt][r]
                 + acc[2][rt][r]*acc[2][rt][r] + acc[3][rt][r]*acc[3][rt][r];
        ss += __shfl_xor(ss, 1); ss += __shfl_xor(ss, 2);
        ss += __shfl_xor(ss, 4); ss += __shfl_xor(ss, 8);
        float nar2 = fmaxf(ss - h0 * h0, 1e-8f);
        float time = es * frcp(1.f + __expf(-h0)) + 1.0001f;
        float sq   = fsqrt(time * time - 1.f) * frsq(nar2);
        float dm   = dis_s[k * 33 + m];
        float dmsq = dm * sq;
        yacc[rt][r][0] += (cl == 0) ? dm * time : dmsq * acc[0][rt][r];
        yacc[rt][r][1] += dmsq * acc[1][rt][r];
        yacc[rt][r][2] += dmsq * acc[2][rt][r];
        yacc[rt][r][3] += dmsq * acc[3][rt][r];
      }
  }
  // one LDS write after both passes
  #pragma unroll
  for (int rt = 0; rt < 2; ++rt)
    #pragma unroll
    for (int r = 0; r < 4; ++r) {
      const int m = rt * 16 + gr * 4 + r;
      float* rw = &red_w[w4][m * 68];
      rw[cl]      = yacc[rt][r][0];
      rw[16 + cl] = yacc[rt][r][1];
      rw[32 + cl] = yacc[rt][r][2];
      rw[48 + cl] = yacc[rt][r][3];
    }
  __syncthreads();

  // ---- final: normalize per (m), mean over m, normalize per node (deterministic)
  {
    const int m  = t >> 3;
    const int l8 = t & 7;
    const int o0 = l8 * 8;
    f4v s0 = (f4v){0.f,0.f,0.f,0.f}, s1 = s0;
    #pragma unroll
    for (int w = 0; w < 4; ++w) {
      s0 += *(const f4v*)&red_w[w][m * 68 + o0];
      s1 += *(const f4v*)&red_w[w][m * 68 + o0 + 4];
    }
    float v[8] = {s0.x, s0.y, s0.z, s0.w, s1.x, s1.y, s1.z, s1.w};
    float ip = 0.f;
    #pragma unroll
    for (int j = 0; j < 8; ++j) ip += v[j] * v[j];
    if (l8 == 0) ip -= 2.f * v[0] * v[0];
    ip += __shfl_xor(ip, 1); ip += __shfl_xor(ip, 2); ip += __shfl_xor(ip, 4);
    float rin = frsq(fmaxf(fabsf(ip), 1e-8f));
    #pragma unroll
    for (int j = 0; j < 8; ++j) {
      float z = v[j] * rin;
      z += __shfl_xor(z, 8); z += __shfl_xor(z, 16); z += __shfl_xor(z, 32);
      v[j] = z;   // sum over this wave's 8 m
    }
    if (l < 8) {
      #pragma unroll
      for (int j = 0; j < 8; ++j) redp[w4 * D + l8 * 8 + j] = v[j];
    }
  }
  __syncthreads();
  if (t < D) {
    float mv = (redp[t] + redp[D + t] + redp[2 * D + t] + redp[3 * D + t]) * (1.f / 32.f);
    float ip = (t == 0) ? -mv * mv : mv * mv;
    #pragma unroll
    for (int s2 = 1; s2 < 64; s2 <<= 1) ip += __shfl_xor(ip, s2);
    out[n * D + t] = mv * frsq(fmaxf(fabsf(ip), 1e-8f));
  }
}

extern "C" void kernel_launch(void* const* d_in, const int* in_sizes, int n_in,
                              void* d_out, int out_size, void* d_ws, size_t ws_size,
                              hipStream_t stream) {
  const float* x     = (const float*)d_in[0];
  const int*   nei   = (const int*)d_in[1];
  const int*   mask  = (const int*)d_in[2];
  const float* W     = (const float*)d_in[3];
  const float* b     = (const float*)d_in[4];
  const float* scale = (const float*)d_in[5];
  const float* kp    = (const float*)d_in[6];
  float* out = (float*)d_out;

  ushort* WF = (ushort*)d_ws;               // 64 frags x 2 parts x 512 ushort = 128 KiB
  float*  xk = (float*)(WF + 65536);        // 8*64 floats

  prep_wb<<<16, 256, 0, stream>>>(W, WF);
  prep_xk<<<1, 64, 0, stream>>>(kp, xk);
  kpa_main<<<N_NODES, 256, 0, stream>>>(x, nei, mask, WF, b, scale, xk, out);
}